// Round 9
// baseline (201.068 us; speedup 1.0000x reference)
//
#include <hip/hip_runtime.h>
#include <hip/hip_bf16.h>
#include <math.h>

// Problem constants
#define TSEQ 4096
#define NB 8
#define DEM 512
#define HD 64
#define LP 72              // flash LDS pitch in bf16 elems (144 B)
#define WIP 136            // W chunk-image pitch (bf16)
#define WIMG 26624         // shorts per chunk image (53248 B = 13 * 4096)
#define QSZ ((size_t)NB * TSEQ * HD)
#define NSLOT 144          // segments per batch (8-tile segments, 128-row q-tiles)

typedef __attribute__((ext_vector_type(8))) short short8;   // 8 bf16 MFMA frag
typedef __attribute__((ext_vector_type(4))) short short4v;  // 8B packed bf16x4
typedef __attribute__((ext_vector_type(4))) float float4v;  // MFMA C/D frag

// fp32 -> bf16 RNE (scalar)
__device__ __forceinline__ short f2bf(float f) {
    union { float f; unsigned u; } v; v.f = f;
    unsigned r = v.u + 0x7fffu + ((v.u >> 16) & 1u);
    return (short)(r >> 16);
}

// pack 8 fp32 -> short8 bf16 via v_cvt_pk
__device__ __forceinline__ short8 pack8(float4 a, float4 b) {
    union { short8 s; __hip_bfloat162 h[4]; } u;
    u.h[0] = __float22bfloat162_rn(make_float2(a.x, a.y));
    u.h[1] = __float22bfloat162_rn(make_float2(a.z, a.w));
    u.h[2] = __float22bfloat162_rn(make_float2(b.x, b.y));
    u.h[3] = __float22bfloat162_rn(make_float2(b.z, b.w));
    return u.s;
}

// pack 4 fp32 -> short4v bf16 via v_cvt_pk
__device__ __forceinline__ short4v pack4(float a, float b, float c, float d) {
    union { short4v s; __hip_bfloat162 h[2]; } u;
    u.h[0] = __float22bfloat162_rn(make_float2(a, b));
    u.h[1] = __float22bfloat162_rn(make_float2(c, d));
    return u.s;
}

// async global->LDS DMA, 16B per lane (dest = wave-uniform base + lane*16)
__device__ __forceinline__ void gload_lds16(const void* g, void* l) {
    __builtin_amdgcn_global_load_lds(
        (const __attribute__((address_space(1))) unsigned int*)g,
        (__attribute__((address_space(3))) unsigned int*)l,
        16, 0, 0);
}

// 8-tile segments: nseg(mq) = (mq>>2)+1; cumulative slot base
__device__ __host__ __forceinline__ int slot_base8(int mq) {
    int a = mq >> 2, bq = mq & 3;
    return (a + 1) * (2 * a + bq);
}

// ---------------------------------------------------------------------------
// W^T precompute -> 4 chunk images [192 n][136 pitch] bf16; softmax scale AND
// log2(e) folded into Wq (so flash uses exp2 directly).
// ---------------------------------------------------------------------------
__global__ __launch_bounds__(256) void wtr_kernel(
    const float* __restrict__ Wq, const float* __restrict__ Wk,
    const float* __restrict__ Wv, short* __restrict__ wimg)
{
    __shared__ float t[64][65];
    const int tid = threadIdx.x;
    const int kb = blockIdx.x;           // 64-k block 0..7
    const int k0 = kb * 64;
    const int m = blockIdx.y;
    const int c = kb >> 1, half = kb & 1;
    const float* W = (m == 0) ? Wq : ((m == 1) ? Wk : Wv);
    // 512^-0.5 * log2(e): scores come out pre-multiplied for exp2
    const float sc = (m == 0) ? 0.063758715f : 1.0f;

#pragma unroll
    for (int i = 0; i < 4; ++i) {
        int f = tid + 256 * i;
        int k = f >> 4, n4 = (f & 15) * 4;
        float4 wv = *(const float4*)&W[(k0 + k) * HD + n4];
        t[k][n4 + 0] = wv.x; t[k][n4 + 1] = wv.y;
        t[k][n4 + 2] = wv.z; t[k][n4 + 3] = wv.w;
    }
    __syncthreads();
#pragma unroll
    for (int i = 0; i < 4; ++i) {
        int f = tid + 256 * i;
        int n = f >> 4, k4 = (f & 15) * 4;
        short4v o;
        o[0] = f2bf(t[k4 + 0][n] * sc);
        o[1] = f2bf(t[k4 + 1][n] * sc);
        o[2] = f2bf(t[k4 + 2][n] * sc);
        o[3] = f2bf(t[k4 + 3][n] * sc);
        *(short4v*)&wimg[c * WIMG + (64 * m + n) * WIP + half * 64 + k4] = o;
    }
}

// ---------------------------------------------------------------------------
// QKV projection: W^T chunk staged in LDS via global_load_lds(16B), shared by
// all 4 waves. Block: 256 thr = 4 waves x 16 rows; grid 512 = 2 blocks/CU.
// ---------------------------------------------------------------------------
__global__ __launch_bounds__(256, 2) void qkv_mfma(
    const float* __restrict__ x, const short* __restrict__ wimg,
    short* __restrict__ q, short* __restrict__ k, short* __restrict__ vt)
{
    __shared__ alignas(16) short wlds[WIMG];   // 53.2 KB, one chunk image

    const int tid = threadIdx.x;
    const int w = tid >> 6;
    const int l15 = tid & 15;
    const int quad = (tid >> 4) & 3;
    const int rbase = blockIdx.x * 64 + w * 16 + l15;   // global row (b*T + t)

    const float* xr = x + (size_t)rbase * DEM;
    float4v acc[12] = {};

    for (int c = 0; c < 4; ++c) {
        __syncthreads();                 // previous chunk's reads complete
        {
            const char* gsrc = (const char*)(wimg + c * WIMG) + tid * 16;
            char* ldst = (char*)wlds + tid * 16;
#pragma unroll
            for (int i = 0; i < 13; ++i)
                gload_lds16(gsrc + i * 4096, ldst + i * 4096);
        }
        __syncthreads();                 // vmcnt(0)+barrier: DMA landed

#pragma unroll
        for (int ks = 0; ks < 4; ++ks) {
            const int k0 = c * 128 + ks * 32 + quad * 8;
            float4 xa = *(const float4*)&xr[k0];
            float4 xb = *(const float4*)&xr[k0 + 4];
            short8 xv = pack8(xa, xb);
            const int lk = ks * 32 + quad * 8;
#pragma unroll
            for (int mt = 0; mt < 12; ++mt) {
                short8 wf = *(const short8*)&wlds[(mt * 16 + l15) * WIP + lk];
                acc[mt] = __builtin_amdgcn_mfma_f32_16x16x32_bf16(wf, xv, acc[mt], 0, 0, 0);
            }
        }
    }

    // Epilogue. C^T frag: row = n_out = mt*16+quad*4+reg, col = t = rbase.
#pragma unroll
    for (int mt = 0; mt < 8; ++mt) {     // q (mt<4), k (mt 4..7): packed 8B
        short* dst = (mt < 4) ? q : k;
        short4v o;
        o[0] = f2bf(acc[mt][0]); o[1] = f2bf(acc[mt][1]);
        o[2] = f2bf(acc[mt][2]); o[3] = f2bf(acc[mt][3]);
        *(short4v*)&dst[(size_t)rbase * HD + (mt & 3) * 16 + quad * 4] = o;
    }
    const int b = rbase >> 12, t = rbase & (TSEQ - 1);
#pragma unroll
    for (int mt = 8; mt < 12; ++mt) {    // v transposed: scalar bf16 stores
#pragma unroll
        for (int reg = 0; reg < 4; ++reg) {
            int d = (mt - 8) * 16 + quad * 4 + reg;
            vt[((size_t)(b * HD + d)) * TSEQ + t] = f2bf(acc[mt][reg]);
        }
    }
}

// ---------------------------------------------------------------------------
// Flash attention phase A. One block = 128 q-rows x one 8-TILE key segment
// (1152 blocks = 4.5/CU -> real 4-deep residency). Fixed-max softmax with
// p = exp2(S) (log2e pre-folded into Wq). Denominator accumulated as an MFMA
// (P @ ones) into Lacc — no VALU adds, no shuffles; Lacc's C-layout matches
// O's rows lane-for-lane so normalization is a per-lane divide.
// mq<=3 (single segment) writes `out` directly; else partials to ws.
// ---------------------------------------------------------------------------
__global__ __launch_bounds__(256, 4) void flash_mfma(
    const short* __restrict__ qw, const short* __restrict__ kw,
    const short* __restrict__ vtw, float* __restrict__ out,
    float* __restrict__ pO, float* __restrict__ stS)
{
    __shared__ short kt[64 * LP];        // K tile [key][d]
    __shared__ short vt[64 * LP];        // V^T tile [d][key]
    __shared__ short pt[4][32 * LP];     // per-wave P [qrow 32][key 64]

    const int tid = threadIdx.x;
    const int w = tid >> 6;
    const int l15 = tid & 15;
    const int quad = (tid >> 4) & 3;
    const int bx = blockIdx.x;
    const int b = bx & 7;
    const int idx = bx >> 3;             // 0..143, mq descending (LPT-ish)

    int mq = 0, j = 0;
    {
        int t = idx;
#pragma unroll 1
        for (int mm = 31; mm >= 0; --mm) {
            int f = (mm >> 2) + 1;       // nseg(mm)
            if (t < f) { mq = mm; j = t; break; }
            t -= f;
        }
    }
    const int s0 = 8 * j;
    const int send = min(8 * (j + 1), 2 * mq + 2);
    const int r0 = mq * 128;
    const int slot = b * NSLOT + slot_base8(mq) + j;

    // Q B-frags in registers: rows r0 + 32w + 16g + l15 (pre-scaled via Wq)
    short8 qf[2][2];
#pragma unroll
    for (int g = 0; g < 2; ++g) {
        const short* qrow = qw + ((size_t)(b * TSEQ + r0 + 32 * w + 16 * g + l15)) * HD;
        qf[g][0] = *(const short8*)(qrow + quad * 8);
        qf[g][1] = *(const short8*)(qrow + 32 + quad * 8);
    }

    // ones B-frag (bf16 1.0) for the P-row-sum MFMA
    short8 ones;
#pragma unroll
    for (int i = 0; i < 8; ++i) ones[i] = (short)0x3F80;

    float4v O[2][4] = {};
    float4v Lacc[2] = {};                // row-sum of P, same C-layout as O

    const int srow = tid >> 3, sc = tid & 7;   // staging coords
    const short* kbase = kw + (size_t)b * TSEQ * HD;
    const short* vbase = vtw + (size_t)b * HD * TSEQ;

    // prefetch first tile into registers
    short8 kr0, kr1, vr0, vr1;
    {
        const short* kg = kbase + (size_t)(s0 * 64) * HD;
        const short* vg = vbase + s0 * 64;
        kr0 = *(const short8*)(kg + srow * HD + sc * 8);
        kr1 = *(const short8*)(kg + (srow + 32) * HD + sc * 8);
        vr0 = *(const short8*)(vg + (size_t)srow * TSEQ + sc * 8);
        vr1 = *(const short8*)(vg + (size_t)(srow + 32) * TSEQ + sc * 8);
    }

    for (int st = s0; st < send; ++st) {
        __syncthreads();   // previous iter done reading kt/vt
        *(short8*)&kt[srow * LP + sc * 8] = kr0;
        *(short8*)&kt[(srow + 32) * LP + sc * 8] = kr1;
        *(short8*)&vt[srow * LP + sc * 8] = vr0;
        *(short8*)&vt[(srow + 32) * LP + sc * 8] = vr1;
        __syncthreads();

        if (st + 1 < send) {   // prefetch next tile
            const short* kg = kbase + (size_t)((st + 1) * 64) * HD;
            const short* vg = vbase + (st + 1) * 64;
            kr0 = *(const short8*)(kg + srow * HD + sc * 8);
            kr1 = *(const short8*)(kg + (srow + 32) * HD + sc * 8);
            vr0 = *(const short8*)(vg + (size_t)srow * TSEQ + sc * 8);
            vr1 = *(const short8*)(vg + (size_t)(srow + 32) * TSEQ + sc * 8);
        }

        // S^T = K @ Q^T : 4 key m-tiles x 2 q-groups; kt A-frags shared
        float4v S[2][4] = {};
#pragma unroll
        for (int mt = 0; mt < 4; ++mt) {
            short8 a0 = *(const short8*)&kt[(mt * 16 + l15) * LP + quad * 8];
            short8 a1 = *(const short8*)&kt[(mt * 16 + l15) * LP + 32 + quad * 8];
            S[0][mt] = __builtin_amdgcn_mfma_f32_16x16x32_bf16(a0, qf[0][0], S[0][mt], 0, 0, 0);
            S[0][mt] = __builtin_amdgcn_mfma_f32_16x16x32_bf16(a1, qf[0][1], S[0][mt], 0, 0, 0);
            S[1][mt] = __builtin_amdgcn_mfma_f32_16x16x32_bf16(a0, qf[1][0], S[1][mt], 0, 0, 0);
            S[1][mt] = __builtin_amdgcn_mfma_f32_16x16x32_bf16(a1, qf[1][1], S[1][mt], 0, 0, 0);
        }

        // causal mask (diag tiles st in {2mq, 2mq+1} — final segment only)
        if (st >= 2 * mq) {
            const int kb2 = st * 64;
#pragma unroll
            for (int g = 0; g < 2; ++g) {
                int qg = r0 + 32 * w + 16 * g + l15;
#pragma unroll
                for (int mt = 0; mt < 4; ++mt)
#pragma unroll
                    for (int r = 0; r < 4; ++r)
                        if (kb2 + mt * 16 + quad * 4 + r > qg) S[g][mt][r] = -INFINITY;
            }
        }

        // p = exp2(S) (log2e folded into q); pack to bf16 P in LDS
#pragma unroll
        for (int g = 0; g < 2; ++g) {
#pragma unroll
            for (int mt = 0; mt < 4; ++mt) {
                float p0 = exp2f(S[g][mt][0]);
                float p1 = exp2f(S[g][mt][1]);
                float p2 = exp2f(S[g][mt][2]);
                float p3 = exp2f(S[g][mt][3]);
                *(short4v*)&pt[w][(16 * g + l15) * LP + mt * 16 + quad * 4] =
                    pack4(p0, p1, p2, p3);
            }
        }

        // O += P @ V ; L += P @ ones (denominator via matrix pipe)
#pragma unroll
        for (int kf = 0; kf < 2; ++kf) {
            short8 pa0 = *(const short8*)&pt[w][l15 * LP + kf * 32 + quad * 8];
            short8 pa1 = *(const short8*)&pt[w][(16 + l15) * LP + kf * 32 + quad * 8];
            Lacc[0] = __builtin_amdgcn_mfma_f32_16x16x32_bf16(pa0, ones, Lacc[0], 0, 0, 0);
            Lacc[1] = __builtin_amdgcn_mfma_f32_16x16x32_bf16(pa1, ones, Lacc[1], 0, 0, 0);
#pragma unroll
            for (int nt = 0; nt < 4; ++nt) {
                short8 vb = *(const short8*)&vt[(nt * 16 + l15) * LP + kf * 32 + quad * 8];
                O[0][nt] = __builtin_amdgcn_mfma_f32_16x16x32_bf16(pa0, vb, O[0][nt], 0, 0, 0);
                O[1][nt] = __builtin_amdgcn_mfma_f32_16x16x32_bf16(pa1, vb, O[1][nt], 0, 0, 0);
            }
        }
    }

    if (mq <= 3) {
        // single segment: normalize (Lacc row-matches O lane-for-lane), store
#pragma unroll
        for (int g = 0; g < 2; ++g)
#pragma unroll
            for (int r = 0; r < 4; ++r) {
                float ir = 1.0f / Lacc[g][r];
                size_t row = (size_t)(b * TSEQ + r0 + 32 * w + 16 * g + quad * 4 + r) * HD;
#pragma unroll
                for (int nt = 0; nt < 4; ++nt)
                    out[row + nt * 16 + l15] = O[g][nt][r] * ir;
            }
    } else {
        float* dest = pO + (size_t)slot * 128 * HD;
#pragma unroll
        for (int g = 0; g < 2; ++g) {
#pragma unroll
            for (int r = 0; r < 4; ++r) {
                size_t row = (size_t)(32 * w + 16 * g + quad * 4 + r) * HD;
#pragma unroll
                for (int nt = 0; nt < 4; ++nt)
                    dest[row + nt * 16 + l15] = O[g][nt][r];
                if (l15 == quad * 4 + r)
                    stS[slot * 128 + 32 * w + 16 * g + quad * 4 + r] = Lacc[g][r];
            }
        }
    }
}

// ---------------------------------------------------------------------------
// Merge: rows with mq>=4 (2..8 segments). 64 rows/block, 4 threads/row.
// grid = 8 batches x 56 blocks = 448.
// ---------------------------------------------------------------------------
__global__ __launch_bounds__(256) void merge_kernel(
    float* __restrict__ out, const float* __restrict__ pO,
    const float* __restrict__ stS)
{
    const int tid = threadIdx.x;
    const int bx = blockIdx.x;
    const int b = bx / 56, loc = bx - b * 56;
    const int t = 512 + loc * 64 + (tid >> 2);       // row within batch
    const int dq = (tid & 3) * 16;
    const int mq = t >> 7, rr = t & 127;
    const int nseg = (mq >> 2) + 1;
    const int sb = b * NSLOT + slot_base8(mq);

    float denom = 0.f;
    for (int s = 0; s < nseg; ++s) denom += stS[(sb + s) * 128 + rr];
    float inv = 1.0f / denom;

    float4 o[4] = {};
    for (int s = 0; s < nseg; ++s) {
        const float4* pp = (const float4*)
            &pO[((size_t)(sb + s) * 128 + rr) * HD + dq];
#pragma unroll
        for (int i = 0; i < 4; ++i) {
            float4 p = pp[i];
            o[i].x += p.x; o[i].y += p.y;
            o[i].z += p.z; o[i].w += p.w;
        }
    }
    float4* op = (float4*)&out[((size_t)b * TSEQ + t) * HD + dq];
#pragma unroll
    for (int i = 0; i < 4; ++i) {
        o[i].x *= inv; o[i].y *= inv; o[i].z *= inv; o[i].w *= inv;
        op[i] = o[i];
    }
}

extern "C" void kernel_launch(void* const* d_in, const int* in_sizes, int n_in,
                              void* d_out, int out_size, void* d_ws, size_t ws_size,
                              hipStream_t stream) {
    const float* x  = (const float*)d_in[0];   // [8, 4096, 512]
    const float* Wq = (const float*)d_in[1];   // [512, 64]
    const float* Wk = (const float*)d_in[2];
    const float* Wv = (const float*)d_in[3];
    float* out = (float*)d_out;                // [8, 4096, 64] fp32

    short* q  = (short*)d_ws;                  // bf16 [8*4096][64], pre-scaled
    short* k  = q + QSZ;                       // bf16 [8*4096][64]
    short* vt = k + QSZ;                       // bf16 [8][64][4096] (transposed)
    short* wimg = vt + QSZ;                    // 4 x chunk image [192][136] bf16
    float* pO = (float*)(wimg + 4 * WIMG);     // 1152 slots x [128][64] fp32 = 37.7 MB
    float* stS = pO + (size_t)NB * NSLOT * 128 * HD;  // 1152 x 128 denominators

    wtr_kernel<<<dim3(8, 3), 256, 0, stream>>>(Wq, Wk, Wv, wimg);
    qkv_mfma<<<dim3(NB * TSEQ / 64), 256, 0, stream>>>(x, wimg, q, k, vt);
    flash_mfma<<<dim3(NB * NSLOT), 256, 0, stream>>>(q, k, vt, out, pO, stS);
    merge_kernel<<<dim3(448), 256, 0, stream>>>(out, pO, stS);
}